// Round 6
// baseline (473.293 us; speedup 1.0000x reference)
//
#include <hip/hip_runtime.h>

typedef short bf16x8 __attribute__((ext_vector_type(8)));
typedef float f32x4 __attribute__((ext_vector_type(4)));

#define K_CLUSTERS 512
#define DIM 64
#define ROWS_PER_BLOCK 64   // 4 subtiles of 16 rows
#define NSUB 4
#define QPAD 516            // 512 + 4 dwords: multiple of 4 (b128-aligned rows)

__device__ __forceinline__ unsigned short f32_to_bf16_rne(float f) {
    unsigned int u = __float_as_uint(f);
    u += 0x7fffu + ((u >> 16) & 1u);
    return (unsigned short)(u >> 16);
}
__device__ __forceinline__ float bf16_bits_to_f32(unsigned short h) {
    return __uint_as_float(((unsigned int)h) << 16);
}

// Centers -> bf16 hi/lo split + ||c||^2. Also zero-inits the loss accumulator.
// (r3 launch structure restored: r5's persistent+fused variant serialized
//  group g+1's z-load vmcnt wait against group g's q-store drain.)
__global__ void prep_centers(const float* __restrict__ c,
                             short* __restrict__ c_hi, short* __restrict__ c_lo,
                             float* __restrict__ c_sq, float* __restrict__ loss_out) {
    if (blockIdx.x == 0 && threadIdx.x == 0) loss_out[0] = 0.0f;
    int idx = blockIdx.x * 256 + threadIdx.x;   // covers 512*64
    float v = c[idx];
    unsigned short h = f32_to_bf16_rne(v);
    float hf = bf16_bits_to_f32(h);
    unsigned short l = f32_to_bf16_rne(v - hf);
    c_hi[idx] = (short)h;
    c_lo[idx] = (short)l;
    float s = v * v;
    #pragma unroll
    for (int off = 1; off < 64; off <<= 1) s += __shfl_xor(s, off, 64);
    if ((threadIdx.x & 63) == 0) c_sq[idx >> 6] = s;
}

// LDS-only barrier: lgkmcnt wait + s_barrier, NO vmcnt drain (q-stores are
// never waited on inside the subtile loop; they drain under compute).
#define BARRIER() do {                                      \
    asm volatile("s_waitcnt lgkmcnt(0)" ::: "memory");      \
    __builtin_amdgcn_s_barrier();                           \
} while (0)

// ROUND-6 CHANGE vs r3 (337.5us): swapped-operand MFMA softmax.
// mfma(c_frag, z_frag) instead of mfma(z_frag, c_frag): each lane's 16 acc
// regs are 16 CLUSTERS of its OWN z-row (row = m = lane&15, cluster =
// wave*64 + t*16 + qd*4 + r). The softmax reduction becomes lane-local:
//   - min/sum over wave's 64 clusters: 15 reg-fmin + 2 shfl_xor (was 32 swizzles)
//   - per-row (mn,invS) distribute: GONE (lane owns its row; was 8 bpermutes)
//   - q_s transpose write: 4x ds_write_b128 (was 16x ds_write_b32)
//   - exp-rescale: q = e * exp(mn-mnw)*invS, e kept from the sum pass
// DS-pipe work per wave-subtile ~470 -> ~170 cyc; DS is per-CU shared, and
// the r0/r2/r3 equality at ~165us points at it as the common bottleneck.
__global__ __launch_bounds__(512, 4)
void cluster_kernel(const float* __restrict__ z,
                    const short* __restrict__ c_hi,
                    const short* __restrict__ c_lo,
                    const float* __restrict__ c_sq,
                    float* __restrict__ q_out,
                    float* __restrict__ loss_out,
                    float inv_b) {
    __shared__ __align__(16) short a_hi_s[NSUB][16][72];   // 144B rows = 9x16B
    __shared__ __align__(16) short a_lo_s[NSUB][16][72];
    __shared__ __align__(16) float q_s[16][QPAD];          // 33 KB q transpose
    __shared__ __align__(16) float2 red_s[2][8][16];       // [parity][wave][row]
    __shared__ float wloss_s[8];

    const int tid  = threadIdx.x;
    const int lane = tid & 63;
    const int wave = tid >> 6;
    const int m    = lane & 15;   // z-row within subtile (D col after swap)
    const int qd   = lane >> 4;   // quad: selects cluster sub-block qd*4..+4
    const int srow = tid >> 5;
    const int scol = (tid & 31) * 2;
    const long rb  = (long)blockIdx.x * ROWS_PER_BLOCK;

    // ---- C fragments (A-operand now): 64 cols/wave = 4 tiles, hi+lo ----
    // Lane layout identical to the old B-frag (lane&15 -> cluster-in-tile,
    // lane>>4 -> k-group), so the loads are unchanged.
    bf16x8 bh[4][2], bl[4][2];
    #pragma unroll
    for (int t = 0; t < 4; ++t) {
        const int col = wave * 64 + t * 16 + m;
        const long boff = (long)col * DIM + qd * 8;
        #pragma unroll
        for (int kg = 0; kg < 2; ++kg) {
            bh[t][kg] = *(const bf16x8*)(c_hi + boff + kg * 32);
            bl[t][kg] = *(const bf16x8*)(c_lo + boff + kg * 32);
        }
    }
    // csq for the lane's OUTPUT clusters: t*16 + qd*4 .. +4 (f32x4 each).
    f32x4 csq4[4];
    #pragma unroll
    for (int t = 0; t < 4; ++t)
        csq4[t] = *(const f32x4*)(c_sq + wave * 64 + t * 16 + qd * 4);

    // ---- prologue: load ALL z rows for this block, cvt+stage to LDS ----
    const float2* zin = (const float2*)(z + rb * DIM);   // 2048 float2
    float zpart = 0.0f;   // per-thread sum of z^2 (separable loss term)
    #pragma unroll
    for (int k = 0; k < NSUB; ++k) {
        float2 v = zin[k * 512 + tid];
        zpart += v.x * v.x + v.y * v.y;
        unsigned short hx = f32_to_bf16_rne(v.x);
        unsigned short lx = f32_to_bf16_rne(v.x - bf16_bits_to_f32(hx));
        unsigned short hy = f32_to_bf16_rne(v.y);
        unsigned short ly = f32_to_bf16_rne(v.y - bf16_bits_to_f32(hy));
        *(unsigned int*)&a_hi_s[k][srow][scol] = (unsigned int)hx | ((unsigned int)hy << 16);
        *(unsigned int*)&a_lo_s[k][srow][scol] = (unsigned int)lx | ((unsigned int)ly << 16);
    }
    BARRIER();   // A staged; read-only for the rest of the kernel

    float lsum = 0.0f;   // per-lane sum of q*(csq-2cross)

    for (int s = 0; s < NSUB; ++s) {
        // ---- Z fragments (B-operand now): lane m holds row m ----
        bf16x8 ah[2], al[2];
        #pragma unroll
        for (int kg = 0; kg < 2; ++kg) {
            ah[kg] = *(const bf16x8*)&a_hi_s[s][m][kg * 32 + qd * 8];
            al[kg] = *(const bf16x8*)&a_lo_s[s][m][kg * 32 + qd * 8];
        }

        // ---- cross^T = c_hi.z_hi + c_lo.z_hi + c_hi.z_lo (near-fp32) ----
        // D[row=cluster(reg), col=z-row(m)]: acc[t][r] = cluster t*16+qd*4+r.
        f32x4 acc[4];
        #pragma unroll
        for (int t = 0; t < 4; ++t) acc[t] = (f32x4){0.f, 0.f, 0.f, 0.f};
        #pragma unroll
        for (int kg = 0; kg < 2; ++kg) {
            #pragma unroll
            for (int t = 0; t < 4; ++t) {
                acc[t] = __builtin_amdgcn_mfma_f32_16x16x32_bf16(bh[t][kg], ah[kg], acc[t], 0, 0, 0);
                acc[t] = __builtin_amdgcn_mfma_f32_16x16x32_bf16(bl[t][kg], ah[kg], acc[t], 0, 0, 0);
                acc[t] = __builtin_amdgcn_mfma_f32_16x16x32_bf16(bh[t][kg], al[kg], acc[t], 0, 0, 0);
            }
        }

        // ---- dd = csq - 2*cross (zsq cancels in softmax) ----
        float dd[4][4];
        #pragma unroll
        for (int t = 0; t < 4; ++t)
            #pragma unroll
            for (int r = 0; r < 4; ++r)
                dd[t][r] = __builtin_fmaf(-2.0f, acc[t][r], csq4[t][r]);

        // ---- lane-local reduce over 16 clusters, then 2 shfl (qd axis) ----
        float mn0;
        {
            float a0 = fminf(fminf(dd[0][0], dd[0][1]), fminf(dd[0][2], dd[0][3]));
            float a1 = fminf(fminf(dd[1][0], dd[1][1]), fminf(dd[1][2], dd[1][3]));
            float a2 = fminf(fminf(dd[2][0], dd[2][1]), fminf(dd[2][2], dd[2][3]));
            float a3 = fminf(fminf(dd[3][0], dd[3][1]), fminf(dd[3][2], dd[3][3]));
            mn0 = fminf(fminf(a0, a1), fminf(a2, a3));
        }
        mn0 = fminf(mn0, __shfl_xor(mn0, 16, 64));
        mn0 = fminf(mn0, __shfl_xor(mn0, 32, 64));
        const float mnw = mn0;   // wave-local min for row m

        float e[4][4], ssum = 0.0f, ped = 0.0f;
        #pragma unroll
        for (int t = 0; t < 4; ++t)
            #pragma unroll
            for (int r = 0; r < 4; ++r) {
                e[t][r] = __expf(mnw - dd[t][r]);
                ssum += e[t][r];
                ped  = __builtin_fmaf(e[t][r], dd[t][r], ped);   // dd dies here
            }
        ssum += __shfl_xor(ssum, 16, 64);
        ssum += __shfl_xor(ssum, 32, 64);

        if (qd == 0)   // lanes 0..15: one b64 each, conflict-free
            red_s[s & 1][wave][m] = make_float2(mnw, ssum);
        BARRIER();   // sync A: partials visible

        // ---- combine across waves (lane's own row m; broadcast reads) ----
        float mn = red_s[s & 1][0][m].x;
        #pragma unroll
        for (int w2 = 1; w2 < 8; ++w2) mn = fminf(mn, red_s[s & 1][w2][m].x);
        float S = 0.0f;
        #pragma unroll
        for (int w2 = 0; w2 < 8; ++w2) {
            float2 p = red_s[s & 1][w2][m];
            S = __builtin_fmaf(p.y, __expf(mn - p.x), S);
        }
        const float fac = __expf(mn - mnw) / S;   // rescale for OUR wave's e

        // ---- q = e * fac -> q_s, 4x ds_write_b128 (row m, packed r) ----
        #pragma unroll
        for (int t = 0; t < 4; ++t) {
            f32x4 qv4;
            #pragma unroll
            for (int r = 0; r < 4; ++r) qv4[r] = e[t][r] * fac;
            *(f32x4*)&q_s[m][wave * 64 + t * 16 + qd * 4] = qv4;
        }
        lsum = __builtin_fmaf(fac, ped, lsum);
        BARRIER();   // sync B: q_s complete

        // ---- coalesced q write: PLAIN dwordx4, 1 KB/instr/wave ----
        const long rbase = rb + (long)s * 16;
        #pragma unroll
        for (int rr = 0; rr < 2; ++rr) {
            const int row = wave * 2 + rr;
            const f32x4* src = (const f32x4*)&q_s[row][0];
            f32x4 v0 = src[lane];
            f32x4 v1 = src[64 + lane];
            f32x4* dst = (f32x4*)(q_out + (rbase + row) * K_CLUSTERS);
            dst[lane]      = v0;
            dst[64 + lane] = v1;
        }
        // no trailing barrier: next q_s writes are 2 barriers away, and each
        // wave's q_s reads complete before its stores issue (lgkmcnt dep).
    }

    // ---- final loss: zsq separable term + q*dd partials ----
    float tot = lsum + zpart;
    #pragma unroll
    for (int off = 1; off < 64; off <<= 1) tot += __shfl_xor(tot, off, 64);
    if (lane == 0) wloss_s[wave] = tot;
    __syncthreads();
    if (tid == 0) {
        float t0 = 0.f;
        #pragma unroll
        for (int w = 0; w < 8; ++w) t0 += wloss_s[w];
        atomicAdd(loss_out, t0 * inv_b);
    }
}

extern "C" void kernel_launch(void* const* d_in, const int* in_sizes, int n_in,
                              void* d_out, int out_size, void* d_ws, size_t ws_size,
                              hipStream_t stream) {
    const float* z = (const float*)d_in[0];
    const float* c = (const float*)d_in[1];
    const int B = in_sizes[0] / DIM;              // 131072
    float* q_out = (float*)d_out;
    float* loss_out = q_out + (size_t)B * K_CLUSTERS;

    char* ws = (char*)d_ws;
    short* c_hi = (short*)ws;                     // 64 KB
    short* c_lo = (short*)(ws + 65536);           // 64 KB
    float* c_sq = (float*)(ws + 131072);          // 2 KB

    prep_centers<<<(K_CLUSTERS * DIM) / 256, 256, 0, stream>>>(c, c_hi, c_lo, c_sq, loss_out);
    cluster_kernel<<<B / ROWS_PER_BLOCK, 512, 0, stream>>>(z, c_hi, c_lo, c_sq, q_out,
                                                           loss_out, 1.0f / (float)B);
}

// Round 7
// 354.197 us; speedup vs baseline: 1.3362x; 1.3362x over previous
//
#include <hip/hip_runtime.h>

typedef short bf16x8 __attribute__((ext_vector_type(8)));
typedef float f32x4 __attribute__((ext_vector_type(4)));

#define K_CLUSTERS 512
#define DIM 64
#define ROWS_PER_BLOCK 64   // 4 subtiles of 16 rows
#define NSUB 4
#define QPAD 520            // 512 + 8 dwords: breaks pow2 bank stride

__device__ __forceinline__ unsigned short f32_to_bf16_rne(float f) {
    unsigned int u = __float_as_uint(f);
    u += 0x7fffu + ((u >> 16) & 1u);
    return (unsigned short)(u >> 16);
}
__device__ __forceinline__ float bf16_bits_to_f32(unsigned short h) {
    return __uint_as_float(((unsigned int)h) << 16);
}

// Centers -> bf16 hi/lo split + ||c||^2. Also zero-inits the loss accumulator.
__global__ void prep_centers(const float* __restrict__ c,
                             short* __restrict__ c_hi, short* __restrict__ c_lo,
                             float* __restrict__ c_sq, float* __restrict__ loss_out) {
    if (blockIdx.x == 0 && threadIdx.x == 0) loss_out[0] = 0.0f;
    int idx = blockIdx.x * 256 + threadIdx.x;   // covers 512*64
    float v = c[idx];
    unsigned short h = f32_to_bf16_rne(v);
    float hf = bf16_bits_to_f32(h);
    unsigned short l = f32_to_bf16_rne(v - hf);
    c_hi[idx] = (short)h;
    c_lo[idx] = (short)l;
    float s = v * v;
    #pragma unroll
    for (int off = 1; off < 64; off <<= 1) s += __shfl_xor(s, off, 64);
    if ((threadIdx.x & 63) == 0) c_sq[idx >> 6] = s;
}

// LDS-only barrier: lgkmcnt wait + s_barrier, NO vmcnt drain (q-stores are
// never waited on inside the subtile loop; they drain under compute).
#define BARRIER() do {                                      \
    asm volatile("s_waitcnt lgkmcnt(0)" ::: "memory");      \
    __builtin_amdgcn_s_barrier();                           \
} while (0)

// ROUND-7: r3 structure VERBATIM except the launch bound.
// r6's counters proved __launch_bounds__(512,4) is interpreted as min 4
// BLOCKS/CU (CUDA semantics): observed VGPR_Count=64 (= 512-reg SIMD file /
// 8 waves), forcing the ~115-reg live set (64 regs of B-fragments alone) to
// spill ~700 MB/dispatch of scratch traffic (FETCH 343 MB vs 34 expected,
// WRITE 671 MB vs 268). Every round this session ran under that hidden cap —
// which is why r0/r2/r3's structural rewrites were all pinned at ~165 us.
// (512,2) -> min 2 blocks/CU = 4 waves/SIMD -> 128-VGPR cap: no spill.
__global__ __launch_bounds__(512, 2)
void cluster_kernel(const float* __restrict__ z,
                    const short* __restrict__ c_hi,
                    const short* __restrict__ c_lo,
                    const float* __restrict__ c_sq,
                    float* __restrict__ q_out,
                    float* __restrict__ loss_out,
                    float inv_b) {
    __shared__ __align__(16) short a_hi_s[NSUB][16][72];   // 144B rows = 9x16B
    __shared__ __align__(16) short a_lo_s[NSUB][16][72];
    __shared__ __align__(16) float q_s[16][QPAD];          // 33.3 KB q transpose
    __shared__ __align__(16) float2 red_s[2][8][16];       // [parity][wave][row]
    __shared__ float wloss_s[8];

    const int tid  = threadIdx.x;
    const int lane = tid & 63;
    const int wave = tid >> 6;
    const int m    = lane & 15;   // A row / B,C col within tile
    const int qd   = lane >> 4;   // quad
    const long rb  = (long)blockIdx.x * ROWS_PER_BLOCK;

    // ---- B fragments (64 cols/wave = 4 tiles): 64 VGPRs hi+lo. ----
    bf16x8 bh[4][2], bl[4][2];
    float csq[4];
    #pragma unroll
    for (int t = 0; t < 4; ++t) {
        const int col = wave * 64 + t * 16 + m;
        const long boff = (long)col * DIM + qd * 8;
        #pragma unroll
        for (int kg = 0; kg < 2; ++kg) {
            bh[t][kg] = *(const bf16x8*)(c_hi + boff + kg * 32);
            bl[t][kg] = *(const bf16x8*)(c_lo + boff + kg * 32);
        }
        csq[t] = c_sq[col];
    }

    // ---- prologue: load ALL z rows for this block, cvt+stage to LDS ----
    const float2* zin = (const float2*)(z + rb * DIM);   // 2048 float2
    const int srow = tid >> 5;
    const int scol = (tid & 31) * 2;
    float zpart = 0.0f;   // per-thread sum of z^2 (separable loss term)
    #pragma unroll
    for (int k = 0; k < NSUB; ++k) {
        float2 v = zin[k * 512 + tid];
        zpart += v.x * v.x + v.y * v.y;
        unsigned short hx = f32_to_bf16_rne(v.x);
        unsigned short lx = f32_to_bf16_rne(v.x - bf16_bits_to_f32(hx));
        unsigned short hy = f32_to_bf16_rne(v.y);
        unsigned short ly = f32_to_bf16_rne(v.y - bf16_bits_to_f32(hy));
        *(unsigned int*)&a_hi_s[k][srow][scol] = (unsigned int)hx | ((unsigned int)hy << 16);
        *(unsigned int*)&a_lo_s[k][srow][scol] = (unsigned int)lx | ((unsigned int)ly << 16);
    }
    BARRIER();   // A staged; A-tiles are read-only from here on

    float lsum = 0.0f;   // per-lane sum of q*(csq-2cross)

    for (int s = 0; s < NSUB; ++s) {
        // ---- A fragments: lane m holds row m, k = kg*32 + qd*8 .. +8 ----
        bf16x8 ah[2], al[2];
        #pragma unroll
        for (int kg = 0; kg < 2; ++kg) {
            ah[kg] = *(const bf16x8*)&a_hi_s[s][m][kg * 32 + qd * 8];
            al[kg] = *(const bf16x8*)&a_lo_s[s][m][kg * 32 + qd * 8];
        }

        // ---- cross = z_hi.c_hi + z_hi.c_lo + z_lo.c_hi (near-fp32) ----
        f32x4 acc[4];
        #pragma unroll
        for (int t = 0; t < 4; ++t) acc[t] = (f32x4){0.f, 0.f, 0.f, 0.f};
        #pragma unroll
        for (int kg = 0; kg < 2; ++kg) {
            #pragma unroll
            for (int t = 0; t < 4; ++t) {
                acc[t] = __builtin_amdgcn_mfma_f32_16x16x32_bf16(ah[kg], bh[t][kg], acc[t], 0, 0, 0);
                acc[t] = __builtin_amdgcn_mfma_f32_16x16x32_bf16(ah[kg], bl[t][kg], acc[t], 0, 0, 0);
                acc[t] = __builtin_amdgcn_mfma_f32_16x16x32_bf16(al[kg], bh[t][kg], acc[t], 0, 0, 0);
            }
        }

        // ---- dd = csq - 2*cross (zsq cancels in softmax) ----
        float dd[4][4];
        #pragma unroll
        for (int t = 0; t < 4; ++t)
            #pragma unroll
            for (int r = 0; r < 4; ++r)
                dd[t][r] = __builtin_fmaf(-2.0f, acc[t][r], csq[t]);

        // ---- per-wave partials: min + sum-exp (16-lane qd-group) ----
        float mnw[4], sw4[4];
        #pragma unroll
        for (int r = 0; r < 4; ++r) {
            float mn0 = fminf(fminf(dd[0][r], dd[1][r]), fminf(dd[2][r], dd[3][r]));
            #pragma unroll
            for (int off = 1; off < 16; off <<= 1)
                mn0 = fminf(mn0, __shfl_xor(mn0, off, 64));
            mnw[r] = mn0;
        }
        #pragma unroll
        for (int r = 0; r < 4; ++r) {
            float s0 = (__expf(mnw[r] - dd[0][r]) + __expf(mnw[r] - dd[1][r]))
                     + (__expf(mnw[r] - dd[2][r]) + __expf(mnw[r] - dd[3][r]));
            #pragma unroll
            for (int off = 1; off < 16; off <<= 1)
                s0 += __shfl_xor(s0, off, 64);
            sw4[r] = s0;
        }
        if (m == 0) {
            #pragma unroll
            for (int r = 0; r < 4; ++r)
                red_s[s & 1][wave][qd * 4 + r] = make_float2(mnw[r], sw4[r]);
        }
        BARRIER();   // sync A: partials visible

        // ---- combine across waves (row = m; broadcast reads) ----
        float mn = red_s[s & 1][0][m].x;
        #pragma unroll
        for (int w2 = 1; w2 < 8; ++w2) mn = fminf(mn, red_s[s & 1][w2][m].x);
        float S = 0.0f;
        #pragma unroll
        for (int w2 = 0; w2 < 8; ++w2) {
            float2 p = red_s[s & 1][w2][m];
            S = __builtin_fmaf(p.y, __expf(mn - p.x), S);
        }
        const float invS = 1.0f / S;

        float mnr[4], fsr[4];
        #pragma unroll
        for (int r = 0; r < 4; ++r) {
            mnr[r] = __shfl(mn,   qd * 4 + r, 64);
            fsr[r] = __shfl(invS, qd * 4 + r, 64);
        }

        // ---- q = exp(mn - dd)*invS -> LDS transpose ----
        #pragma unroll
        for (int r = 0; r < 4; ++r) {
            const int row = qd * 4 + r;
            #pragma unroll
            for (int t = 0; t < 4; ++t) {
                const float qv = __expf(mnr[r] - dd[t][r]) * fsr[r];
                q_s[row][wave * 64 + t * 16 + m] = qv;
                lsum = __builtin_fmaf(qv, dd[t][r], lsum);
            }
        }
        BARRIER();   // sync B: q_s complete

        // ---- coalesced q write: PLAIN dwordx4, 1 KB/instr/wave ----
        const long rbase = rb + (long)s * 16;
        #pragma unroll
        for (int rr = 0; rr < 2; ++rr) {
            const int row = wave * 2 + rr;
            const f32x4* src = (const f32x4*)&q_s[row][0];
            f32x4 v0 = src[lane];
            f32x4 v1 = src[64 + lane];
            f32x4* dst = (f32x4*)(q_out + (rbase + row) * K_CLUSTERS);
            dst[lane]      = v0;
            dst[64 + lane] = v1;
        }
        // no trailing barrier: next q_s writes are 2 barriers away
    }

    // ---- final loss: zsq separable term + q*dd partials ----
    float tot = lsum + zpart;
    #pragma unroll
    for (int off = 1; off < 64; off <<= 1) tot += __shfl_xor(tot, off, 64);
    if (lane == 0) wloss_s[wave] = tot;
    __syncthreads();
    if (tid == 0) {
        float t0 = 0.f;
        #pragma unroll
        for (int w = 0; w < 8; ++w) t0 += wloss_s[w];
        atomicAdd(loss_out, t0 * inv_b);
    }
}

extern "C" void kernel_launch(void* const* d_in, const int* in_sizes, int n_in,
                              void* d_out, int out_size, void* d_ws, size_t ws_size,
                              hipStream_t stream) {
    const float* z = (const float*)d_in[0];
    const float* c = (const float*)d_in[1];
    const int B = in_sizes[0] / DIM;              // 131072
    float* q_out = (float*)d_out;
    float* loss_out = q_out + (size_t)B * K_CLUSTERS;

    char* ws = (char*)d_ws;
    short* c_hi = (short*)ws;                     // 64 KB
    short* c_lo = (short*)(ws + 65536);           // 64 KB
    float* c_sq = (float*)(ws + 131072);          // 2 KB

    prep_centers<<<(K_CLUSTERS * DIM) / 256, 256, 0, stream>>>(c, c_hi, c_lo, c_sq, loss_out);
    cluster_kernel<<<B / ROWS_PER_BLOCK, 512, 0, stream>>>(z, c_hi, c_lo, c_sq, q_out,
                                                           loss_out, 1.0f / (float)B);
}

// Round 8
// 336.326 us; speedup vs baseline: 1.4072x; 1.0531x over previous
//
#include <hip/hip_runtime.h>

typedef short bf16x8 __attribute__((ext_vector_type(8)));
typedef float f32x4 __attribute__((ext_vector_type(4)));

#define K_CLUSTERS 512
#define DIM 64
#define ROWS_PER_BLOCK 64   // 4 subtiles of 16 rows
#define NSUB 4
#define QPAD 516            // 512 + 4 dwords: multiple of 4 (b128-aligned rows)

__device__ __forceinline__ unsigned short f32_to_bf16_rne(float f) {
    unsigned int u = __float_as_uint(f);
    u += 0x7fffu + ((u >> 16) & 1u);
    return (unsigned short)(u >> 16);
}
__device__ __forceinline__ float bf16_bits_to_f32(unsigned short h) {
    return __uint_as_float(((unsigned int)h) << 16);
}

// Centers -> bf16 hi/lo split + ||c||^2. Also zero-inits the loss accumulator.
__global__ void prep_centers(const float* __restrict__ c,
                             short* __restrict__ c_hi, short* __restrict__ c_lo,
                             float* __restrict__ c_sq, float* __restrict__ loss_out) {
    if (blockIdx.x == 0 && threadIdx.x == 0) loss_out[0] = 0.0f;
    int idx = blockIdx.x * 256 + threadIdx.x;   // covers 512*64
    float v = c[idx];
    unsigned short h = f32_to_bf16_rne(v);
    float hf = bf16_bits_to_f32(h);
    unsigned short l = f32_to_bf16_rne(v - hf);
    c_hi[idx] = (short)h;
    c_lo[idx] = (short)l;
    float s = v * v;
    #pragma unroll
    for (int off = 1; off < 64; off <<= 1) s += __shfl_xor(s, off, 64);
    if ((threadIdx.x & 63) == 0) c_sq[idx >> 6] = s;
}

// LDS-only barrier: lgkmcnt wait + s_barrier, NO vmcnt drain (q-stores are
// never waited on inside the subtile loop; they drain under compute).
#define BARRIER() do {                                      \
    asm volatile("s_waitcnt lgkmcnt(0)" ::: "memory");      \
    __builtin_amdgcn_s_barrier();                           \
} while (0)

// ROUND-8: r6's swapped-MFMA kernel VERBATIM except __launch_bounds__(512,2).
// Evidence chain:
//  * r6 proved bounds(512,4) = min 4 BLOCKS/CU (CUDA semantics): VGPR_Count=64,
//    and the swapped kernel's cross-barrier live set (~105 regs: 64 B-frags +
//    16 e + 16 csq) spilled ~700 MB/dispatch scratch (FETCH 343 MB, WRITE
//    655 MB, 4 TB/s, 253 us) -- the DS-reduction mechanism was never tested.
//  * r3-vs-r7 showed the OLD DS-heavy softmax prefers 32 waves/CU even with
//    spill; but its per-phase DS work (~500 cyc/wave-subtile) is exactly what
//    this structure removes (~170 cyc: swizzles 32->4, bpermutes 8->0,
//    q_s writes 16xb32 -> 4xb128).
// (512,2): 128-reg cap -> live set fits, no spill, 16 waves/CU.
__global__ __launch_bounds__(512, 2)
void cluster_kernel(const float* __restrict__ z,
                    const short* __restrict__ c_hi,
                    const short* __restrict__ c_lo,
                    const float* __restrict__ c_sq,
                    float* __restrict__ q_out,
                    float* __restrict__ loss_out,
                    float inv_b) {
    __shared__ __align__(16) short a_hi_s[NSUB][16][72];   // 144B rows = 9x16B
    __shared__ __align__(16) short a_lo_s[NSUB][16][72];
    __shared__ __align__(16) float q_s[16][QPAD];          // 33 KB q transpose
    __shared__ __align__(16) float2 red_s[2][8][16];       // [parity][wave][row]
    __shared__ float wloss_s[8];

    const int tid  = threadIdx.x;
    const int lane = tid & 63;
    const int wave = tid >> 6;
    const int m    = lane & 15;   // z-row within subtile (D col after swap)
    const int qd   = lane >> 4;   // quad: selects cluster sub-block qd*4..+4
    const int srow = tid >> 5;
    const int scol = (tid & 31) * 2;
    const long rb  = (long)blockIdx.x * ROWS_PER_BLOCK;

    // ---- C fragments (A-operand): 64 clusters/wave = 4 tiles, hi+lo ----
    bf16x8 bh[4][2], bl[4][2];
    #pragma unroll
    for (int t = 0; t < 4; ++t) {
        const int col = wave * 64 + t * 16 + m;
        const long boff = (long)col * DIM + qd * 8;
        #pragma unroll
        for (int kg = 0; kg < 2; ++kg) {
            bh[t][kg] = *(const bf16x8*)(c_hi + boff + kg * 32);
            bl[t][kg] = *(const bf16x8*)(c_lo + boff + kg * 32);
        }
    }
    // csq for the lane's OUTPUT clusters: t*16 + qd*4 .. +4 (f32x4 each).
    f32x4 csq4[4];
    #pragma unroll
    for (int t = 0; t < 4; ++t)
        csq4[t] = *(const f32x4*)(c_sq + wave * 64 + t * 16 + qd * 4);

    // ---- prologue: load ALL z rows for this block, cvt+stage to LDS ----
    const float2* zin = (const float2*)(z + rb * DIM);   // 2048 float2
    float zpart = 0.0f;   // per-thread sum of z^2 (separable loss term)
    #pragma unroll
    for (int k = 0; k < NSUB; ++k) {
        float2 v = zin[k * 512 + tid];
        zpart += v.x * v.x + v.y * v.y;
        unsigned short hx = f32_to_bf16_rne(v.x);
        unsigned short lx = f32_to_bf16_rne(v.x - bf16_bits_to_f32(hx));
        unsigned short hy = f32_to_bf16_rne(v.y);
        unsigned short ly = f32_to_bf16_rne(v.y - bf16_bits_to_f32(hy));
        *(unsigned int*)&a_hi_s[k][srow][scol] = (unsigned int)hx | ((unsigned int)hy << 16);
        *(unsigned int*)&a_lo_s[k][srow][scol] = (unsigned int)lx | ((unsigned int)ly << 16);
    }
    BARRIER();   // A staged; read-only for the rest of the kernel

    float lsum = 0.0f;   // per-lane sum of q*(csq-2cross)

    for (int s = 0; s < NSUB; ++s) {
        // ---- Z fragments (B-operand): lane m holds row m ----
        bf16x8 ah[2], al[2];
        #pragma unroll
        for (int kg = 0; kg < 2; ++kg) {
            ah[kg] = *(const bf16x8*)&a_hi_s[s][m][kg * 32 + qd * 8];
            al[kg] = *(const bf16x8*)&a_lo_s[s][m][kg * 32 + qd * 8];
        }

        // ---- cross^T = c_hi.z_hi + c_lo.z_hi + c_hi.z_lo (near-fp32) ----
        // D[row=cluster(reg), col=z-row(m)]: acc[t][r] = cluster t*16+qd*4+r.
        f32x4 acc[4];
        #pragma unroll
        for (int t = 0; t < 4; ++t) acc[t] = (f32x4){0.f, 0.f, 0.f, 0.f};
        #pragma unroll
        for (int kg = 0; kg < 2; ++kg) {
            #pragma unroll
            for (int t = 0; t < 4; ++t) {
                acc[t] = __builtin_amdgcn_mfma_f32_16x16x32_bf16(bh[t][kg], ah[kg], acc[t], 0, 0, 0);
                acc[t] = __builtin_amdgcn_mfma_f32_16x16x32_bf16(bl[t][kg], ah[kg], acc[t], 0, 0, 0);
                acc[t] = __builtin_amdgcn_mfma_f32_16x16x32_bf16(bh[t][kg], al[kg], acc[t], 0, 0, 0);
            }
        }

        // ---- dd = csq - 2*cross (zsq cancels in softmax) ----
        float dd[4][4];
        #pragma unroll
        for (int t = 0; t < 4; ++t)
            #pragma unroll
            for (int r = 0; r < 4; ++r)
                dd[t][r] = __builtin_fmaf(-2.0f, acc[t][r], csq4[t][r]);

        // ---- lane-local reduce over 16 clusters, then 2 shfl (qd axis) ----
        float mn0;
        {
            float a0 = fminf(fminf(dd[0][0], dd[0][1]), fminf(dd[0][2], dd[0][3]));
            float a1 = fminf(fminf(dd[1][0], dd[1][1]), fminf(dd[1][2], dd[1][3]));
            float a2 = fminf(fminf(dd[2][0], dd[2][1]), fminf(dd[2][2], dd[2][3]));
            float a3 = fminf(fminf(dd[3][0], dd[3][1]), fminf(dd[3][2], dd[3][3]));
            mn0 = fminf(fminf(a0, a1), fminf(a2, a3));
        }
        mn0 = fminf(mn0, __shfl_xor(mn0, 16, 64));
        mn0 = fminf(mn0, __shfl_xor(mn0, 32, 64));
        const float mnw = mn0;   // wave-local min for row m

        float e[4][4], ssum = 0.0f, ped = 0.0f;
        #pragma unroll
        for (int t = 0; t < 4; ++t)
            #pragma unroll
            for (int r = 0; r < 4; ++r) {
                e[t][r] = __expf(mnw - dd[t][r]);
                ssum += e[t][r];
                ped  = __builtin_fmaf(e[t][r], dd[t][r], ped);   // dd dies here
            }
        ssum += __shfl_xor(ssum, 16, 64);
        ssum += __shfl_xor(ssum, 32, 64);

        if (qd == 0)   // lanes 0..15: one b64 each, conflict-free
            red_s[s & 1][wave][m] = make_float2(mnw, ssum);
        BARRIER();   // sync A: partials visible

        // ---- combine across waves (lane's own row m; broadcast reads) ----
        float mn = red_s[s & 1][0][m].x;
        #pragma unroll
        for (int w2 = 1; w2 < 8; ++w2) mn = fminf(mn, red_s[s & 1][w2][m].x);
        float S = 0.0f;
        #pragma unroll
        for (int w2 = 0; w2 < 8; ++w2) {
            float2 p = red_s[s & 1][w2][m];
            S = __builtin_fmaf(p.y, __expf(mn - p.x), S);
        }
        const float fac = __expf(mn - mnw) / S;   // rescale for OUR wave's e

        // ---- q = e * fac -> q_s, 4x ds_write_b128 (row m, packed r) ----
        #pragma unroll
        for (int t = 0; t < 4; ++t) {
            f32x4 qv4;
            #pragma unroll
            for (int r = 0; r < 4; ++r) qv4[r] = e[t][r] * fac;
            *(f32x4*)&q_s[m][wave * 64 + t * 16 + qd * 4] = qv4;
        }
        lsum = __builtin_fmaf(fac, ped, lsum);
        BARRIER();   // sync B: q_s complete

        // ---- coalesced q write: PLAIN dwordx4, 1 KB/instr/wave ----
        const long rbase = rb + (long)s * 16;
        #pragma unroll
        for (int rr = 0; rr < 2; ++rr) {
            const int row = wave * 2 + rr;
            const f32x4* src = (const f32x4*)&q_s[row][0];
            f32x4 v0 = src[lane];
            f32x4 v1 = src[64 + lane];
            f32x4* dst = (f32x4*)(q_out + (rbase + row) * K_CLUSTERS);
            dst[lane]      = v0;
            dst[64 + lane] = v1;
        }
        // no trailing barrier: next q_s writes are 2 barriers away, and each
        // wave's q_s reads complete before its stores issue (lgkmcnt dep).
    }

    // ---- final loss: zsq separable term + q*dd partials ----
    float tot = lsum + zpart;
    #pragma unroll
    for (int off = 1; off < 64; off <<= 1) tot += __shfl_xor(tot, off, 64);
    if (lane == 0) wloss_s[wave] = tot;
    __syncthreads();
    if (tid == 0) {
        float t0 = 0.f;
        #pragma unroll
        for (int w = 0; w < 8; ++w) t0 += wloss_s[w];
        atomicAdd(loss_out, t0 * inv_b);
    }
}

extern "C" void kernel_launch(void* const* d_in, const int* in_sizes, int n_in,
                              void* d_out, int out_size, void* d_ws, size_t ws_size,
                              hipStream_t stream) {
    const float* z = (const float*)d_in[0];
    const float* c = (const float*)d_in[1];
    const int B = in_sizes[0] / DIM;              // 131072
    float* q_out = (float*)d_out;
    float* loss_out = q_out + (size_t)B * K_CLUSTERS;

    char* ws = (char*)d_ws;
    short* c_hi = (short*)ws;                     // 64 KB
    short* c_lo = (short*)(ws + 65536);           // 64 KB
    float* c_sq = (float*)(ws + 131072);          // 2 KB

    prep_centers<<<(K_CLUSTERS * DIM) / 256, 256, 0, stream>>>(c, c_hi, c_lo, c_sq, loss_out);
    cluster_kernel<<<B / ROWS_PER_BLOCK, 512, 0, stream>>>(z, c_hi, c_lo, c_sq, q_out,
                                                           loss_out, 1.0f / (float)B);
}